// Round 2
// baseline (373.215 us; speedup 1.0000x reference)
//
#include <hip/hip_runtime.h>

typedef unsigned short u16;
typedef __bf16 bf16x8 __attribute__((ext_vector_type(8)));
typedef float f32x4 __attribute__((ext_vector_type(4)));

#define LOG2E 1.44269504088896f

__device__ inline u16 f2b(float f) {
    unsigned u = __float_as_uint(f);
    u += 0x7fff + ((u >> 16) & 1);
    return (u16)(u >> 16);
}
__device__ inline float b2f(u16 u) { return __uint_as_float(((unsigned)u) << 16); }
__device__ inline unsigned pk2(float a, float b) {
    return (unsigned)f2b(a) | ((unsigned)f2b(b) << 16);
}
__device__ inline uint4 pack8(float4 a, float4 b) {
    return uint4{pk2(a.x, a.y), pk2(a.z, a.w), pk2(b.x, b.y), pk2(b.z, b.w)};
}

__device__ inline f32x4 mfma_bf16(uint4 a, uint4 b, f32x4 c) {
    return __builtin_amdgcn_mfma_f32_16x16x32_bf16(
        __builtin_bit_cast(bf16x8, a), __builtin_bit_cast(bf16x8, b), c, 0, 0, 0);
}

// ---------------------------------------------------------------------------
// Weight prep (f32 -> bf16):
//   WkT[e][d] = Wqk[1][d][e],  WvT[e][d] = Wv[d][e],  Wqb[c][d] = Wqk[0][c][d]
// ---------------------------------------------------------------------------
__global__ __launch_bounds__(256) void prep_w(const float* __restrict__ Wqk,
                                              const float* __restrict__ Wv,
                                              u16* __restrict__ WkT,
                                              u16* __restrict__ WvT,
                                              u16* __restrict__ Wqb) {
    int idx = blockIdx.x * 256 + threadIdx.x;   // 0 .. 196607
    int which = idx >> 16;
    int i = (idx >> 8) & 255;
    int j = idx & 255;
    if (which == 0)
        WkT[i * 256 + j] = f2b(Wqk[65536 + j * 256 + i]);
    else if (which == 1)
        WvT[i * 256 + j] = f2b(Wv[j * 256 + i]);
    else
        Wqb[i * 256 + j] = f2b(Wqk[i * 256 + j]);
}

// ---------------------------------------------------------------------------
// GEMM with transposed C-write:  C^T[b][col][n] = (A @ Bt^T + bias)^T
// A: (65536 x 256) f32 row-major (rows = b*8192+n), converted to bf16 while
// staging.  Bt: (256 x 256) bf16 row-major (Bt[col][k]).  bias f32.
// Output CT bf16, layout [b][col][8192].  Tile 64x64, 4 waves, K=256.
// ---------------------------------------------------------------------------
__global__ __launch_bounds__(256) void gemm_transC(const float* __restrict__ A,
                                                   const u16* __restrict__ Bt,
                                                   const float* __restrict__ bias,
                                                   u16* __restrict__ CT) {
    __shared__ __align__(16) u16 lds[6144];     // As: [0,3072), Bs: [3072,6144); Ct aliases
    u16* As = lds;
    u16* Bs = lds + 3072;

    const int t = threadIdx.x;
    const int c0 = blockIdx.x * 64;
    const int r0 = blockIdx.y * 64;

    const int tr = t >> 2;
    const int tk = (t & 3) * 8;
    const int w = t >> 6;
    const int lane = t & 63;
    const int l15 = lane & 15;
    const int q = lane >> 4;

    f32x4 acc[4];
#pragma unroll
    for (int c = 0; c < 4; ++c) acc[c] = f32x4{0.f, 0.f, 0.f, 0.f};

    const float* Arow = A + (long)(r0 + tr) * 256 + tk;
    const u16* Brow = Bt + (long)(c0 + tr) * 256 + tk;
    u16* AsW = &As[tr * 48 + tk];
    u16* BsW = &Bs[tr * 48 + tk];
    const u16* AsR = &As[(w * 16 + l15) * 48 + q * 8];
    const u16* BsR = &Bs[l15 * 48 + q * 8];

    for (int k0 = 0; k0 < 256; k0 += 32) {
        float4 a0 = ((const float4*)(Arow + k0))[0];
        float4 a1 = ((const float4*)(Arow + k0))[1];
        uint4 bv = *(const uint4*)(Brow + k0);
        *(uint4*)AsW = pack8(a0, a1);
        *(uint4*)BsW = bv;
        __syncthreads();
        uint4 af = *(const uint4*)AsR;
#pragma unroll
        for (int c = 0; c < 4; ++c) {
            uint4 bf = *(const uint4*)(BsR + c * 16 * 48);
            acc[c] = mfma_bf16(af, bf, acc[c]);
        }
        __syncthreads();
    }

    // epilogue: bias add, transpose through LDS, coalesced write of C^T
    u16* Ct = lds;                              // stride 72 ushorts (144 B, 16B-aligned)
#pragma unroll
    for (int c = 0; c < 4; ++c) {
        float bv = bias[c0 + c * 16 + l15];
#pragma unroll
        for (int r = 0; r < 4; ++r) {
            Ct[(c * 16 + l15) * 72 + (w * 16 + q * 4 + r)] = f2b(acc[c][r] + bv);
        }
    }
    __syncthreads();
    int cc = t >> 2;
    int ng = (t & 3) * 16;
    int bb = r0 >> 13;
    int n0 = r0 & 8191;
    long off = ((long)bb * 256 + (c0 + cc)) * 8192 + n0 + ng;
    uint4 v0 = *(uint4*)&Ct[cc * 72 + ng];
    uint4 v1 = *(uint4*)&Ct[cc * 72 + ng + 8];
    *(uint4*)(CT + off) = v0;
    *(uint4*)(CT + off + 8) = v1;
}

// ---------------------------------------------------------------------------
// Row-major-C GEMM: C[row][col] = sum_k A[row][k]*Bt[col][k] (+ bias[col])
// Ncols fixed = 256.  A is f32 (converted while staging) or bf16.
// Bt bf16, optionally batched by bb = row / rowsPerBatch.  Out f32 or bf16.
// ---------------------------------------------------------------------------
template <bool A_F32, bool OUT_F32, bool BIAS>
__global__ __launch_bounds__(256) void gemm_rowC(const void* __restrict__ Ain,
                                                 const u16* __restrict__ Bt,
                                                 const float* __restrict__ bias,
                                                 void* __restrict__ Cout,
                                                 int K, int rowsPerBatch, long btStride) {
    __shared__ __align__(16) u16 As[64 * 48];
    __shared__ __align__(16) u16 Bs[64 * 48];

    const int t = threadIdx.x;
    const int c0 = blockIdx.x * 64;
    const int r0 = blockIdx.y * 64;
    const int bb = r0 / rowsPerBatch;
    const u16* BtB = Bt + (long)bb * btStride;

    const int tr = t >> 2;
    const int tk = (t & 3) * 8;
    const int w = t >> 6;
    const int lane = t & 63;
    const int l15 = lane & 15;
    const int q = lane >> 4;

    f32x4 acc[4];
#pragma unroll
    for (int c = 0; c < 4; ++c) acc[c] = f32x4{0.f, 0.f, 0.f, 0.f};

    const float* ArowF = (const float*)Ain + (long)(r0 + tr) * K + tk;
    const u16* ArowB = (const u16*)Ain + (long)(r0 + tr) * K + tk;
    const u16* Brow = BtB + (long)(c0 + tr) * K + tk;
    u16* AsW = &As[tr * 48 + tk];
    u16* BsW = &Bs[tr * 48 + tk];
    const u16* AsR = &As[(w * 16 + l15) * 48 + q * 8];
    const u16* BsR = &Bs[l15 * 48 + q * 8];

    for (int k0 = 0; k0 < K; k0 += 32) {
        uint4 av;
        if (A_F32) {
            float4 a0 = ((const float4*)(ArowF + k0))[0];
            float4 a1 = ((const float4*)(ArowF + k0))[1];
            av = pack8(a0, a1);
        } else {
            av = *(const uint4*)(ArowB + k0);
        }
        uint4 bv = *(const uint4*)(Brow + k0);
        *(uint4*)AsW = av;
        *(uint4*)BsW = bv;
        __syncthreads();
        uint4 af = *(const uint4*)AsR;
#pragma unroll
        for (int c = 0; c < 4; ++c) {
            uint4 bf = *(const uint4*)(BsR + c * 16 * 48);
            acc[c] = mfma_bf16(af, bf, acc[c]);
        }
        __syncthreads();
    }

#pragma unroll
    for (int c = 0; c < 4; ++c) {
        int col = c0 + c * 16 + l15;
        float bv = 0.f;
        if (BIAS) bv = bias[(long)bb * 256 + col];
#pragma unroll
        for (int r = 0; r < 4; ++r) {
            int row = r0 + w * 16 + q * 4 + r;
            float v = acc[c][r] + bv;
            if (OUT_F32)
                ((float*)Cout)[(long)row * 256 + col] = v;
            else
                ((u16*)Cout)[(long)row * 256 + col] = f2b(v);
        }
    }
}

// ---------------------------------------------------------------------------
// In-place softmax over each contiguous 8192-row of KT ([b*256+d][8192]).
// One wave per row; two-pass from registers; writes p = exp(k-m)/l (bf16).
// ---------------------------------------------------------------------------
__global__ __launch_bounds__(64) void softmax_rows(u16* __restrict__ KT) {
    const int row = blockIdx.x;
    const int lane = threadIdx.x;
    u16* p = KT + (long)row * 8192;

    uint4 buf[16];
#pragma unroll
    for (int i = 0; i < 16; ++i) buf[i] = *(const uint4*)(p + (i * 64 + lane) * 8);

    float m = -1e30f;
#pragma unroll
    for (int i = 0; i < 16; ++i) {
        const unsigned* u = (const unsigned*)&buf[i];
#pragma unroll
        for (int j = 0; j < 4; ++j) {
            m = fmaxf(m, fmaxf(b2f((u16)(u[j] & 0xffff)), b2f((u16)(u[j] >> 16))));
        }
    }
#pragma unroll
    for (int s = 32; s > 0; s >>= 1) m = fmaxf(m, __shfl_xor(m, s, 64));

    float sum = 0.f;
#pragma unroll
    for (int i = 0; i < 16; ++i) {
        const unsigned* u = (const unsigned*)&buf[i];
#pragma unroll
        for (int j = 0; j < 4; ++j) {
            sum += exp2f((b2f((u16)(u[j] & 0xffff)) - m) * LOG2E);
            sum += exp2f((b2f((u16)(u[j] >> 16)) - m) * LOG2E);
        }
    }
#pragma unroll
    for (int s = 32; s > 0; s >>= 1) sum += __shfl_xor(sum, s, 64);
    float rl = 1.0f / sum;

#pragma unroll
    for (int i = 0; i < 16; ++i) {
        unsigned* u = (unsigned*)&buf[i];
#pragma unroll
        for (int j = 0; j < 4; ++j) {
            float a = exp2f((b2f((u16)(u[j] & 0xffff)) - m) * LOG2E) * rl;
            float b = exp2f((b2f((u16)(u[j] >> 16)) - m) * LOG2E) * rl;
            u[j] = (unsigned)f2b(a) | ((unsigned)f2b(b) << 16);
        }
        *(uint4*)(p + (i * 64 + lane) * 8) = buf[i];
    }
}

// ---------------------------------------------------------------------------
// BatchNorm over lam^T[(b*256+e)][d]: stats per d over 2048 (b,e) values.
// gamma/beta f32.  Writes bn^T[(b*256+e)][d] bf16.
// ---------------------------------------------------------------------------
__global__ __launch_bounds__(256) void bn_kernel(const float* __restrict__ lamT,
                                                 const float* __restrict__ gamma,
                                                 const float* __restrict__ beta,
                                                 u16* __restrict__ bnT) {
    const int d = blockIdx.x;
    const int t = threadIdx.x;
    float vals[8];
    float s = 0.f, ss = 0.f;
#pragma unroll
    for (int i = 0; i < 8; ++i) {
        float v = lamT[(long)(i * 256 + t) * 256 + d];
        vals[i] = v;
        s += v;
        ss += v * v;
    }
#pragma unroll
    for (int sh = 32; sh > 0; sh >>= 1) {
        s += __shfl_xor(s, sh, 64);
        ss += __shfl_xor(ss, sh, 64);
    }
    __shared__ float red[8];
    int w = t >> 6;
    if ((t & 63) == 0) {
        red[w] = s;
        red[w + 4] = ss;
    }
    __syncthreads();
    s = red[0] + red[1] + red[2] + red[3];
    ss = red[4] + red[5] + red[6] + red[7];
    float mean = s * (1.f / 2048.f);
    float var = ss * (1.f / 2048.f) - mean * mean;
    float scale = gamma[d] * rsqrtf(var + 1e-5f);
    float shift = beta[d] - mean * scale;
#pragma unroll
    for (int i = 0; i < 8; ++i)
        bnT[(long)(i * 256 + t) * 256 + d] = f2b(vals[i] * scale + shift);
}

// ---------------------------------------------------------------------------
// outb[b][e] = sum_d bq[d] * bnT[b][e][d]   (folded query bias)
// ---------------------------------------------------------------------------
__global__ __launch_bounds__(256) void outb_kernel(const float* __restrict__ bq,
                                                   const u16* __restrict__ bnT,
                                                   float* __restrict__ outb) {
    int b = blockIdx.x, e = threadIdx.x;
    const u16* rowp = bnT + ((long)b * 256 + e) * 256;
    float s = 0.f;
    for (int dd = 0; dd < 256; ++dd) s += bq[dd] * b2f(rowp[dd]);
    outb[b * 256 + e] = s;
}

// ---------------------------------------------------------------------------
extern "C" void kernel_launch(void* const* d_in, const int* in_sizes, int n_in,
                              void* d_out, int out_size, void* d_ws, size_t ws_size,
                              hipStream_t stream) {
    const float* feat = (const float*)d_in[0];   // (8,8192,256) f32
    const float* W_qk = (const float*)d_in[1];   // (2,256,256) f32
    const float* b_qk = (const float*)d_in[2];   // (2,256) f32
    const float* W_v = (const float*)d_in[3];    // (256,256) f32
    const float* b_v = (const float*)d_in[4];    // (256,) f32
    const float* gamma = (const float*)d_in[5];  // (256,) f32
    const float* beta = (const float*)d_in[6];   // (256,) f32
    float* out = (float*)d_out;                  // (8,8192,256) f32

    char* ws = (char*)d_ws;
    u16* KT = (u16*)(ws);                    // [b][d][n]  33554432 B
    u16* VT = (u16*)(ws + 33554432);         // [b][e][n]  33554432 B
    float* lamT = (float*)(ws + 67108864);   // [(b,e)][d] 2097152 B
    u16* bnT = (u16*)(ws + 69206016);        // [(b,e)][d] 1048576 B
    u16* WkT = (u16*)(ws + 70254592);        // 131072 B
    u16* WvT = (u16*)(ws + 70385664);        // 131072 B
    u16* Wqb = (u16*)(ws + 70516736);        // 131072 B
    u16* WfoldT = (u16*)(ws + 70647808);     // [(b,e)][c] 1048576 B
    float* outb = (float*)(ws + 71696384);   // 8192 B

    // 1. weight prep (bf16 conversions + transposes)
    prep_w<<<768, 256, 0, stream>>>(W_qk, W_v, WkT, WvT, Wqb);
    // 2. K^T = (X@Wk + bk)^T ; V^T = (X@Wv + bv)^T
    gemm_transC<<<dim3(4, 1024), 256, 0, stream>>>(feat, WkT, b_qk + 256, KT);
    gemm_transC<<<dim3(4, 1024), 256, 0, stream>>>(feat, WvT, b_v, VT);
    // 3. in-place softmax over n for each (b,d) row -> P^T
    softmax_rows<<<2048, 64, 0, stream>>>(KT);
    // 4. lam^T[(b,e)][d] = sum_n V^T[e][n] * P^T[d][n]
    gemm_rowC<false, true, false><<<dim3(4, 32), 256, 0, stream>>>(VT, KT, nullptr, lamT,
                                                                   8192, 256, 2097152L);
    // 5. BN -> bn^T bf16
    bn_kernel<<<256, 256, 0, stream>>>(lamT, gamma, beta, bnT);
    // 6. folded query bias: outb[b][e] = sum_d bq[d]*bn[b][d][e]
    outb_kernel<<<8, 256, 0, stream>>>(b_qk, bnT, outb);
    // 7. Wfold^T[(b,e)][c] = sum_d bn^T[(b,e)][d] * Wq[c][d]
    gemm_rowC<false, false, false><<<dim3(4, 32), 256, 0, stream>>>(bnT, Wqb, nullptr,
                                                                    WfoldT, 256, 2048, 0L);
    // 8. out[b][n][e] = sum_c X[b][n][c] * Wfold^T[b][e][c] + outb[b][e]
    gemm_rowC<true, true, true><<<dim3(4, 1024), 256, 0, stream>>>(feat, WfoldT, outb, out,
                                                                   256, 8192, 65536L);
}

// Round 3
// 289.333 us; speedup vs baseline: 1.2899x; 1.2899x over previous
//
#include <hip/hip_runtime.h>

typedef unsigned short u16;
typedef __bf16 bf16x8 __attribute__((ext_vector_type(8)));
typedef float f32x4 __attribute__((ext_vector_type(4)));

#define LOG2E 1.44269504088896f

__device__ inline u16 f2b(float f) {
    unsigned u = __float_as_uint(f);
    u += 0x7fff + ((u >> 16) & 1);
    return (u16)(u >> 16);
}
__device__ inline float b2f(u16 u) { return __uint_as_float(((unsigned)u) << 16); }
__device__ inline unsigned pk2(float a, float b) {
    return (unsigned)f2b(a) | ((unsigned)f2b(b) << 16);
}
__device__ inline uint4 pack8(float4 a, float4 b) {
    return uint4{pk2(a.x, a.y), pk2(a.z, a.w), pk2(b.x, b.y), pk2(b.z, b.w)};
}

__device__ inline f32x4 mfma_bf16(uint4 a, uint4 b, f32x4 c) {
    return __builtin_amdgcn_mfma_f32_16x16x32_bf16(
        __builtin_bit_cast(bf16x8, a), __builtin_bit_cast(bf16x8, b), c, 0, 0, 0);
}

// ---------------------------------------------------------------------------
// Weight prep (f32 -> bf16):
//   WkT[e][d] = Wqk[1][d][e],  WvT[e][d] = Wv[d][e],  Wqb[c][d] = Wqk[0][c][d]
// ---------------------------------------------------------------------------
__global__ __launch_bounds__(256) void prep_w(const float* __restrict__ Wqk,
                                              const float* __restrict__ Wv,
                                              u16* __restrict__ WkT,
                                              u16* __restrict__ WvT,
                                              u16* __restrict__ Wqb) {
    int idx = blockIdx.x * 256 + threadIdx.x;   // 0 .. 196607
    int which = idx >> 16;
    int i = (idx >> 8) & 255;
    int j = idx & 255;
    if (which == 0)
        WkT[i * 256 + j] = f2b(Wqk[65536 + j * 256 + i]);
    else if (which == 1)
        WvT[i * 256 + j] = f2b(Wv[j * 256 + i]);
    else
        Wqb[i * 256 + j] = f2b(Wqk[i * 256 + j]);
}

// ---------------------------------------------------------------------------
// Fused K+V projection with transposed C-write:
//   K^T[b][col][n] = (X @ WkT^T + kb)^T ,  V^T[b][col][n] = (X @ WvT^T + vb)^T
// X: (65536 x 256) f32, converted to bf16 while staging (side-written to Xb
// when blockIdx.x==0 and Xb!=null).  Tile 64x64, 4 waves, K=256, 8 MFMA/step.
// ---------------------------------------------------------------------------
__global__ __launch_bounds__(256) void gemm_kv(const float* __restrict__ A,
                                               const u16* __restrict__ BtK,
                                               const u16* __restrict__ BtV,
                                               const float* __restrict__ biasK,
                                               const float* __restrict__ biasV,
                                               u16* __restrict__ KT,
                                               u16* __restrict__ VT,
                                               u16* __restrict__ Xb) {
    __shared__ __align__(16) u16 lds[9216];   // As[0,3072) BsK[3072,6144) BsV[6144,9216)
    u16* As = lds;
    u16* BsK = lds + 3072;
    u16* BsV = lds + 6144;

    const int t = threadIdx.x;
    const int c0 = blockIdx.x * 64;
    const int r0 = blockIdx.y * 64;

    const int tr = t >> 2;
    const int tk = (t & 3) * 8;
    const int w = t >> 6;
    const int lane = t & 63;
    const int l15 = lane & 15;
    const int q = lane >> 4;

    f32x4 accK[4], accV[4];
#pragma unroll
    for (int c = 0; c < 4; ++c) {
        accK[c] = f32x4{0.f, 0.f, 0.f, 0.f};
        accV[c] = f32x4{0.f, 0.f, 0.f, 0.f};
    }

    const float* Arow = A + (long)(r0 + tr) * 256 + tk;
    const u16* BrowK = BtK + (long)(c0 + tr) * 256 + tk;
    const u16* BrowV = BtV + (long)(c0 + tr) * 256 + tk;
    u16* AsW = &As[tr * 48 + tk];
    u16* BsWK = &BsK[tr * 48 + tk];
    u16* BsWV = &BsV[tr * 48 + tk];
    const u16* AsR = &As[(w * 16 + l15) * 48 + q * 8];
    const u16* BsRK = &BsK[l15 * 48 + q * 8];
    const u16* BsRV = &BsV[l15 * 48 + q * 8];
    const bool writeX = (Xb != nullptr) && (blockIdx.x == 0);
    u16* XbW = Xb + (long)(r0 + tr) * 256 + tk;

    float4 a0 = ((const float4*)Arow)[0];
    float4 a1 = ((const float4*)Arow)[1];
    uint4 bk = *(const uint4*)BrowK;
    uint4 bvv = *(const uint4*)BrowV;

    for (int k0 = 0; k0 < 256; k0 += 32) {
        uint4 ap = pack8(a0, a1);
        *(uint4*)AsW = ap;
        *(uint4*)BsWK = bk;
        *(uint4*)BsWV = bvv;
        if (writeX) *(uint4*)(XbW + k0) = ap;
        __syncthreads();
        if (k0 + 32 < 256) {
            a0 = ((const float4*)(Arow + k0 + 32))[0];
            a1 = ((const float4*)(Arow + k0 + 32))[1];
            bk = *(const uint4*)(BrowK + k0 + 32);
            bvv = *(const uint4*)(BrowV + k0 + 32);
        }
        uint4 af = *(const uint4*)AsR;
#pragma unroll
        for (int c = 0; c < 4; ++c) {
            uint4 bfK = *(const uint4*)(BsRK + c * 16 * 48);
            uint4 bfV = *(const uint4*)(BsRV + c * 16 * 48);
            accK[c] = mfma_bf16(af, bfK, accK[c]);
            accV[c] = mfma_bf16(af, bfV, accV[c]);
        }
        __syncthreads();
    }

    // epilogue: bias add + LDS transpose + coalesced C^T write, K then V
    u16* Ct = lds;                            // stride 72 ushorts
    const int bb = r0 >> 13;
    const int n0 = r0 & 8191;
    const int cc = t >> 2;
    const int ng = (t & 3) * 16;
#pragma unroll
    for (int pass = 0; pass < 2; ++pass) {
        const f32x4* acc = pass ? accV : accK;
        const float* bias = pass ? biasV : biasK;
        u16* CT = pass ? VT : KT;
#pragma unroll
        for (int c = 0; c < 4; ++c) {
            float bv = bias[c0 + c * 16 + l15];
#pragma unroll
            for (int r = 0; r < 4; ++r) {
                Ct[(c * 16 + l15) * 72 + (w * 16 + q * 4 + r)] = f2b(acc[c][r] + bv);
            }
        }
        __syncthreads();
        long off = ((long)bb * 256 + (c0 + cc)) * 8192 + n0 + ng;
        uint4 v0 = *(uint4*)&Ct[cc * 72 + ng];
        uint4 v1 = *(uint4*)&Ct[cc * 72 + ng + 8];
        *(uint4*)(CT + off) = v0;
        *(uint4*)(CT + off + 8) = v1;
        __syncthreads();
    }
}

// ---------------------------------------------------------------------------
// Row-major-C GEMM: C[row][col] = sum_k A[row][k]*Bt[col][k] (+ bias[col])
// Ncols fixed = 256.  A f32 (converted while staging) or bf16.  Bt bf16,
// optionally batched by bb = row / rowsPerBatch.  Out f32 or bf16.
// ---------------------------------------------------------------------------
template <bool A_F32, bool OUT_F32, bool BIAS>
__global__ __launch_bounds__(256) void gemm_rowC(const void* __restrict__ Ain,
                                                 const u16* __restrict__ Bt,
                                                 const float* __restrict__ bias,
                                                 void* __restrict__ Cout,
                                                 int K, int rowsPerBatch, long btStride) {
    __shared__ __align__(16) u16 As[64 * 48];
    __shared__ __align__(16) u16 Bs[64 * 48];

    const int t = threadIdx.x;
    const int c0 = blockIdx.x * 64;
    const int r0 = blockIdx.y * 64;
    const int bb = r0 / rowsPerBatch;
    const u16* BtB = Bt + (long)bb * btStride;

    const int tr = t >> 2;
    const int tk = (t & 3) * 8;
    const int w = t >> 6;
    const int lane = t & 63;
    const int l15 = lane & 15;
    const int q = lane >> 4;

    f32x4 acc[4];
#pragma unroll
    for (int c = 0; c < 4; ++c) acc[c] = f32x4{0.f, 0.f, 0.f, 0.f};

    const float* ArowF = (const float*)Ain + (long)(r0 + tr) * K + tk;
    const u16* ArowB = (const u16*)Ain + (long)(r0 + tr) * K + tk;
    const u16* Brow = BtB + (long)(c0 + tr) * K + tk;
    u16* AsW = &As[tr * 48 + tk];
    u16* BsW = &Bs[tr * 48 + tk];
    const u16* AsR = &As[(w * 16 + l15) * 48 + q * 8];
    const u16* BsR = &Bs[l15 * 48 + q * 8];

    uint4 av;
    float4 a0, a1;
    if (A_F32) {
        a0 = ((const float4*)ArowF)[0];
        a1 = ((const float4*)ArowF)[1];
    } else {
        av = *(const uint4*)ArowB;
    }
    uint4 bv = *(const uint4*)Brow;

    for (int k0 = 0; k0 < K; k0 += 32) {
        *(uint4*)AsW = A_F32 ? pack8(a0, a1) : av;
        *(uint4*)BsW = bv;
        __syncthreads();
        if (k0 + 32 < K) {
            if (A_F32) {
                a0 = ((const float4*)(ArowF + k0 + 32))[0];
                a1 = ((const float4*)(ArowF + k0 + 32))[1];
            } else {
                av = *(const uint4*)(ArowB + k0 + 32);
            }
            bv = *(const uint4*)(Brow + k0 + 32);
        }
        uint4 af = *(const uint4*)AsR;
#pragma unroll
        for (int c = 0; c < 4; ++c) {
            uint4 bf = *(const uint4*)(BsR + c * 16 * 48);
            acc[c] = mfma_bf16(af, bf, acc[c]);
        }
        __syncthreads();
    }

#pragma unroll
    for (int c = 0; c < 4; ++c) {
        int col = c0 + c * 16 + l15;
        float bv2 = 0.f;
        if (BIAS) bv2 = bias[(long)bb * 256 + col];
#pragma unroll
        for (int r = 0; r < 4; ++r) {
            int row = r0 + w * 16 + q * 4 + r;
            float v = acc[c][r] + bv2;
            if (OUT_F32)
                ((float*)Cout)[(long)row * 256 + col] = v;
            else
                ((u16*)Cout)[(long)row * 256 + col] = f2b(v);
        }
    }
}

// ---------------------------------------------------------------------------
// Split-K lam GEMM: lamP[s][(b,e)][d] = sum_{n in chunk s} V^T[(b,e)][n] *
// P^T[(b,d)][n].  Grid (4, 32, S).  Tile 64x64, 4 waves.
// ---------------------------------------------------------------------------
__global__ __launch_bounds__(256) void gemm_splitk(const u16* __restrict__ VT,
                                                   const u16* __restrict__ PT,
                                                   float* __restrict__ lamP,
                                                   int chunk) {
    __shared__ __align__(16) u16 As[64 * 48];
    __shared__ __align__(16) u16 Bs[64 * 48];

    const int t = threadIdx.x;
    const int c0 = blockIdx.x * 64;
    const int r0 = blockIdx.y * 64;
    const int s = blockIdx.z;
    const int bb = r0 >> 8;
    const long n0 = (long)s * chunk;

    const int tr = t >> 2;
    const int tk = (t & 3) * 8;
    const int w = t >> 6;
    const int lane = t & 63;
    const int l15 = lane & 15;
    const int q = lane >> 4;

    f32x4 acc[4];
#pragma unroll
    for (int c = 0; c < 4; ++c) acc[c] = f32x4{0.f, 0.f, 0.f, 0.f};

    const u16* Arow = VT + (long)(r0 + tr) * 8192 + n0 + tk;
    const u16* Brow = PT + ((long)bb * 256 + c0 + tr) * 8192 + n0 + tk;
    u16* AsW = &As[tr * 48 + tk];
    u16* BsW = &Bs[tr * 48 + tk];
    const u16* AsR = &As[(w * 16 + l15) * 48 + q * 8];
    const u16* BsR = &Bs[l15 * 48 + q * 8];

    uint4 av = *(const uint4*)Arow;
    uint4 bv = *(const uint4*)Brow;

    for (int k0 = 0; k0 < chunk; k0 += 32) {
        *(uint4*)AsW = av;
        *(uint4*)BsW = bv;
        __syncthreads();
        if (k0 + 32 < chunk) {
            av = *(const uint4*)(Arow + k0 + 32);
            bv = *(const uint4*)(Brow + k0 + 32);
        }
        uint4 af = *(const uint4*)AsR;
#pragma unroll
        for (int c = 0; c < 4; ++c) {
            uint4 bf = *(const uint4*)(BsR + c * 16 * 48);
            acc[c] = mfma_bf16(af, bf, acc[c]);
        }
        __syncthreads();
    }

    float* outp = lamP + (long)s * 524288;
#pragma unroll
    for (int c = 0; c < 4; ++c) {
        int col = c0 + c * 16 + l15;
#pragma unroll
        for (int r = 0; r < 4; ++r) {
            int row = r0 + w * 16 + q * 4 + r;
            outp[(long)row * 256 + col] = acc[c][r];
        }
    }
}

// ---------------------------------------------------------------------------
// lamT[i] = sum_s lamP[s][i]   (coalesced float4)
// ---------------------------------------------------------------------------
__global__ __launch_bounds__(256) void reduce_lam(const float* __restrict__ lamP,
                                                  float* __restrict__ lamT, int S) {
    int i = blockIdx.x * 256 + threadIdx.x;     // float4 index, 131072 total
    float4 v = ((const float4*)lamP)[i];
    for (int s = 1; s < S; ++s) {
        float4 p = ((const float4*)(lamP + (long)s * 524288))[i];
        v.x += p.x; v.y += p.y; v.z += p.z; v.w += p.w;
    }
    ((float4*)lamT)[i] = v;
}

// ---------------------------------------------------------------------------
// In-place softmax over each contiguous 8192-row of KT ([b*256+d][8192]).
// ---------------------------------------------------------------------------
__global__ __launch_bounds__(64) void softmax_rows(u16* __restrict__ KT) {
    const int row = blockIdx.x;
    const int lane = threadIdx.x;
    u16* p = KT + (long)row * 8192;

    uint4 buf[16];
#pragma unroll
    for (int i = 0; i < 16; ++i) buf[i] = *(const uint4*)(p + (i * 64 + lane) * 8);

    float m = -1e30f;
#pragma unroll
    for (int i = 0; i < 16; ++i) {
        const unsigned* u = (const unsigned*)&buf[i];
#pragma unroll
        for (int j = 0; j < 4; ++j) {
            m = fmaxf(m, fmaxf(b2f((u16)(u[j] & 0xffff)), b2f((u16)(u[j] >> 16))));
        }
    }
#pragma unroll
    for (int s = 32; s > 0; s >>= 1) m = fmaxf(m, __shfl_xor(m, s, 64));

    float sum = 0.f;
#pragma unroll
    for (int i = 0; i < 16; ++i) {
        const unsigned* u = (const unsigned*)&buf[i];
#pragma unroll
        for (int j = 0; j < 4; ++j) {
            sum += exp2f((b2f((u16)(u[j] & 0xffff)) - m) * LOG2E);
            sum += exp2f((b2f((u16)(u[j] >> 16)) - m) * LOG2E);
        }
    }
#pragma unroll
    for (int s = 32; s > 0; s >>= 1) sum += __shfl_xor(sum, s, 64);
    float rl = 1.0f / sum;

#pragma unroll
    for (int i = 0; i < 16; ++i) {
        unsigned* u = (unsigned*)&buf[i];
#pragma unroll
        for (int j = 0; j < 4; ++j) {
            float a = exp2f((b2f((u16)(u[j] & 0xffff)) - m) * LOG2E) * rl;
            float b = exp2f((b2f((u16)(u[j] >> 16)) - m) * LOG2E) * rl;
            u[j] = (unsigned)f2b(a) | ((unsigned)f2b(b) << 16);
        }
        *(uint4*)(p + (i * 64 + lane) * 8) = buf[i];
    }
}

// ---------------------------------------------------------------------------
// BatchNorm over lam^T[(b*256+e)][d]: stats per d over 2048 (b,e) values.
// ---------------------------------------------------------------------------
__global__ __launch_bounds__(256) void bn_kernel(const float* __restrict__ lamT,
                                                 const float* __restrict__ gamma,
                                                 const float* __restrict__ beta,
                                                 u16* __restrict__ bnT) {
    const int d = blockIdx.x;
    const int t = threadIdx.x;
    float vals[8];
    float s = 0.f, ss = 0.f;
#pragma unroll
    for (int i = 0; i < 8; ++i) {
        float v = lamT[(long)(i * 256 + t) * 256 + d];
        vals[i] = v;
        s += v;
        ss += v * v;
    }
#pragma unroll
    for (int sh = 32; sh > 0; sh >>= 1) {
        s += __shfl_xor(s, sh, 64);
        ss += __shfl_xor(ss, sh, 64);
    }
    __shared__ float red[8];
    int w = t >> 6;
    if ((t & 63) == 0) {
        red[w] = s;
        red[w + 4] = ss;
    }
    __syncthreads();
    s = red[0] + red[1] + red[2] + red[3];
    ss = red[4] + red[5] + red[6] + red[7];
    float mean = s * (1.f / 2048.f);
    float var = ss * (1.f / 2048.f) - mean * mean;
    float scale = gamma[d] * rsqrtf(var + 1e-5f);
    float shift = beta[d] - mean * scale;
#pragma unroll
    for (int i = 0; i < 8; ++i)
        bnT[(long)(i * 256 + t) * 256 + d] = f2b(vals[i] * scale + shift);
}

// ---------------------------------------------------------------------------
// outb[b][e] = sum_d bq[d] * bnT[b][e][d]   (folded query bias)
// ---------------------------------------------------------------------------
__global__ __launch_bounds__(256) void outb_kernel(const float* __restrict__ bq,
                                                   const u16* __restrict__ bnT,
                                                   float* __restrict__ outb) {
    int b = blockIdx.x, e = threadIdx.x;
    const u16* rowp = bnT + ((long)b * 256 + e) * 256;
    float s = 0.f;
    for (int dd = 0; dd < 256; ++dd) s += bq[dd] * b2f(rowp[dd]);
    outb[b * 256 + e] = s;
}

// ---------------------------------------------------------------------------
extern "C" void kernel_launch(void* const* d_in, const int* in_sizes, int n_in,
                              void* d_out, int out_size, void* d_ws, size_t ws_size,
                              hipStream_t stream) {
    const float* feat = (const float*)d_in[0];   // (8,8192,256) f32
    const float* W_qk = (const float*)d_in[1];   // (2,256,256) f32
    const float* b_qk = (const float*)d_in[2];   // (2,256) f32
    const float* W_v = (const float*)d_in[3];    // (256,256) f32
    const float* b_v = (const float*)d_in[4];    // (256,) f32
    const float* gamma = (const float*)d_in[5];  // (256,) f32
    const float* beta = (const float*)d_in[6];   // (256,) f32
    float* out = (float*)d_out;                  // (8,8192,256) f32

    char* ws = (char*)d_ws;
    u16* KT = (u16*)(ws);                        // [b][d][n]  33,554,432 B (P after softmax)
    u16* VT = (u16*)(ws + 33554432);             // [b][e][n]  33,554,432 B
    u16* WkT = (u16*)(ws + 67108864);            // 131072 B
    u16* WvT = (u16*)(ws + 67239936);            // 131072 B
    u16* Wqb = (u16*)(ws + 67371008);            // 131072 B
    const size_t base = 67502080;
    float* lamP = (float*)(ws + base);           // S * 2,097,152 B
    size_t avail = (ws_size > base) ? ws_size - base : 0;
    int S = (avail >= 8u * 2097152u) ? 8 : ((avail >= 4u * 2097152u) ? 4 : 2);
    u16* Xb = nullptr;                           // bf16 copy of feature (optional)
    if (avail >= (size_t)S * 2097152u + 33554432u) Xb = (u16*)(ws + base + (size_t)S * 2097152u);
    // post-split-K buffers alias the dead P region (KT):
    float* lamT = (float*)ws;                    // 2,097,152 B
    u16* bnT = (u16*)(ws + 2097152);             // 1,048,576 B
    u16* WfoldT = (u16*)(ws + 3145728);          // 1,048,576 B
    float* outb = (float*)(ws + 4194304);        // 8,192 B

    // 1. weight prep
    prep_w<<<768, 256, 0, stream>>>(W_qk, W_v, WkT, WvT, Wqb);
    // 2. fused K^T / V^T projection (+ bf16 X side-copy)
    gemm_kv<<<dim3(4, 1024), 256, 0, stream>>>(feat, WkT, WvT, b_qk + 256, b_v, KT, VT, Xb);
    // 3. in-place softmax over n -> P^T
    softmax_rows<<<2048, 64, 0, stream>>>(KT);
    // 4. split-K lam partials + reduce
    gemm_splitk<<<dim3(4, 32, S), 256, 0, stream>>>(VT, KT, lamP, 8192 / S);
    reduce_lam<<<512, 256, 0, stream>>>(lamP, lamT, S);
    // 5. BN -> bn^T bf16
    bn_kernel<<<256, 256, 0, stream>>>(lamT, gamma, beta, bnT);
    // 6. folded query bias
    outb_kernel<<<8, 256, 0, stream>>>(b_qk, bnT, outb);
    // 7. Wfold^T[(b,e)][c] = sum_d bn^T[(b,e)][d] * Wq[c][d]
    gemm_rowC<false, false, false><<<dim3(4, 32), 256, 0, stream>>>(bnT, Wqb, nullptr,
                                                                    WfoldT, 256, 2048, 0L);
    // 8. out[b][n][e] = sum_c X[b][n][c] * Wfold^T[b][e][c] + outb[b][e]
    if (Xb)
        gemm_rowC<false, true, true><<<dim3(4, 1024), 256, 0, stream>>>(Xb, WfoldT, outb, out,
                                                                        256, 8192, 65536L);
    else
        gemm_rowC<true, true, true><<<dim3(4, 1024), 256, 0, stream>>>(feat, WfoldT, outb, out,
                                                                       256, 8192, 65536L);
}

// Round 4
// 253.170 us; speedup vs baseline: 1.4742x; 1.1428x over previous
//
#include <hip/hip_runtime.h>

typedef unsigned short u16;
typedef __bf16 bf16x8 __attribute__((ext_vector_type(8)));
typedef float f32x4 __attribute__((ext_vector_type(4)));

#define LOG2E 1.44269504088896f

__device__ inline u16 f2b(float f) {
    unsigned u = __float_as_uint(f);
    u += 0x7fff + ((u >> 16) & 1);
    return (u16)(u >> 16);
}
__device__ inline float b2f(u16 u) { return __uint_as_float(((unsigned)u) << 16); }
__device__ inline unsigned pk2(float a, float b) {
    return (unsigned)f2b(a) | ((unsigned)f2b(b) << 16);
}
__device__ inline uint4 pack8(float4 a, float4 b) {
    return uint4{pk2(a.x, a.y), pk2(a.z, a.w), pk2(b.x, b.y), pk2(b.z, b.w)};
}
__device__ inline f32x4 mfma_bf16(uint4 a, uint4 b, f32x4 c) {
    return __builtin_amdgcn_mfma_f32_16x16x32_bf16(
        __builtin_bit_cast(bf16x8, a), __builtin_bit_cast(bf16x8, b), c, 0, 0, 0);
}
// async global->LDS, 16 B per lane; LDS dest = wave-uniform base + lane*16
__device__ inline void ld16(const u16* g, u16* l) {
    __builtin_amdgcn_global_load_lds(
        (const __attribute__((address_space(1))) unsigned int*)g,
        (__attribute__((address_space(3))) unsigned int*)l, 16, 0, 0);
}

// ---------------------------------------------------------------------------
// Weight prep (f32 -> bf16):
//   WkT[e][d] = Wqk[1][d][e],  WvT[e][d] = Wv[d][e],  Wqb[c][d] = Wqk[0][c][d]
// ---------------------------------------------------------------------------
__global__ __launch_bounds__(256) void prep_w(const float* __restrict__ Wqk,
                                              const float* __restrict__ Wv,
                                              u16* __restrict__ WkT,
                                              u16* __restrict__ WvT,
                                              u16* __restrict__ Wqb) {
    int idx = blockIdx.x * 256 + threadIdx.x;   // 0 .. 196607
    int which = idx >> 16;
    int i = (idx >> 8) & 255;
    int j = idx & 255;
    if (which == 0)
        WkT[i * 256 + j] = f2b(Wqk[65536 + j * 256 + i]);
    else if (which == 1)
        WvT[i * 256 + j] = f2b(Wv[j * 256 + i]);
    else
        Wqb[i * 256 + j] = f2b(Wqk[i * 256 + j]);
}

// ---------------------------------------------------------------------------
// Fused K+V projection, FULL-WIDTH (64 rows x 256 cols x {K,V}) per block.
// A = X (65536 x 256 f32) read exactly once; B slabs (weights, bf16) staged
// per 32-k step via global_load_lds (L2-resident after first blocks).
// C^T epilogue through LDS: KT/VT layout [b][d][8192] bf16.
// ---------------------------------------------------------------------------
__global__ __launch_bounds__(256, 2) void gemm_kv(const float* __restrict__ A,
                                                  const u16* __restrict__ BtK,
                                                  const u16* __restrict__ BtV,
                                                  const float* __restrict__ biasK,
                                                  const float* __restrict__ biasV,
                                                  u16* __restrict__ KT,
                                                  u16* __restrict__ VT) {
    __shared__ __align__(16) u16 lds[18432];  // As[0,2048) BsK[2048,10240) BsV[10240,18432)
    u16* As = lds;          // 64 x 32, unpadded (conflict-free for (l15,q) frags)
    u16* BsK = lds + 2048;  // 256 x 32
    u16* BsV = lds + 10240; // 256 x 32

    const int t = threadIdx.x;
    const int r0 = blockIdx.x * 64;
    const int w = t >> 6, lane = t & 63, l15 = lane & 15, q = lane >> 4;

    f32x4 accK[16], accV[16];
#pragma unroll
    for (int c = 0; c < 16; ++c) {
        accK[c] = f32x4{0.f, 0.f, 0.f, 0.f};
        accV[c] = f32x4{0.f, 0.f, 0.f, 0.f};
    }

    const int ar = t >> 2;            // A staging row (0..63)
    const int ak = (t & 3) * 8;       // A staging k-offset
    const float* Arow = A + (long)(r0 + ar) * 256 + ak;
    u16* AsW = As + t * 8;            // == ar*32 + ak

    float4 a0 = ((const float4*)Arow)[0];
    float4 a1 = ((const float4*)Arow)[1];

    for (int k0 = 0; k0 < 256; k0 += 32) {
        // async-stage B slabs (4 sweeps each): chunk j*256+t -> row,(koff)
#pragma unroll
        for (int j = 0; j < 4; ++j) {
            int ch = j * 256 + t;
            int br = ch >> 2;
            int bk = (ch & 3) * 8;
            ld16(BtK + br * 256 + k0 + bk, BsK + j * 2048 + w * 512);
            ld16(BtV + br * 256 + k0 + bk, BsV + j * 2048 + w * 512);
        }
        *(uint4*)AsW = pack8(a0, a1);
        __syncthreads();
        if (k0 + 32 < 256) {
            a0 = ((const float4*)(Arow + k0 + 32))[0];
            a1 = ((const float4*)(Arow + k0 + 32))[1];
        }
        uint4 af = *(const uint4*)(As + (w * 16 + l15) * 32 + q * 8);
#pragma unroll
        for (int c = 0; c < 16; ++c) {
            uint4 bK = *(const uint4*)(BsK + (c * 16 + l15) * 32 + q * 8);
            uint4 bV = *(const uint4*)(BsV + (c * 16 + l15) * 32 + q * 8);
            accK[c] = mfma_bf16(af, bK, accK[c]);
            accV[c] = mfma_bf16(af, bV, accV[c]);
        }
        __syncthreads();
    }

    // epilogue: bias + transpose through LDS (256 x 72 u16 = 36 KB), K then V
    const int bb = r0 >> 13, n0 = r0 & 8191;
    u16* Ct = lds;
#pragma unroll
    for (int pass = 0; pass < 2; ++pass) {
        const f32x4* acc = pass ? accV : accK;
        const float* bias = pass ? biasV : biasK;
        u16* CT = pass ? VT : KT;
#pragma unroll
        for (int c = 0; c < 16; ++c) {
            float bv = bias[c * 16 + l15];
            ushort4 pk;
            pk.x = f2b(acc[c][0] + bv);
            pk.y = f2b(acc[c][1] + bv);
            pk.z = f2b(acc[c][2] + bv);
            pk.w = f2b(acc[c][3] + bv);
            *(ushort4*)&Ct[(c * 16 + l15) * 72 + w * 16 + q * 4] = pk;
        }
        __syncthreads();
        long off = ((long)bb * 256 + t) * 8192 + n0;
#pragma unroll
        for (int j = 0; j < 8; ++j)
            *(uint4*)(CT + off + j * 8) = *(const uint4*)&Ct[t * 72 + j * 8];
        __syncthreads();
    }
}

// ---------------------------------------------------------------------------
// Output GEMM, FULL-WIDTH: out[b][n][e] = sum_c X[b][n][c]*WfoldT[(b,e)][c]
// + outb[b][e].  64 rows x 256 cols per block, grid 1024.  Out f32.
// ---------------------------------------------------------------------------
__global__ __launch_bounds__(256, 3) void gemm_out(const float* __restrict__ A,
                                                   const u16* __restrict__ WfoldT,
                                                   const float* __restrict__ outb,
                                                   float* __restrict__ C) {
    __shared__ __align__(16) u16 lds[10240];  // As 64x32, Bs 256x32
    u16* As = lds;
    u16* Bs = lds + 2048;

    const int t = threadIdx.x;
    const int r0 = blockIdx.x * 64;
    const int bb = r0 >> 13;
    const int w = t >> 6, lane = t & 63, l15 = lane & 15, q = lane >> 4;
    const u16* Bt = WfoldT + (long)bb * 65536;

    f32x4 acc[16];
#pragma unroll
    for (int c = 0; c < 16; ++c) acc[c] = f32x4{0.f, 0.f, 0.f, 0.f};

    const float* Arow = A + (long)(r0 + (t >> 2)) * 256 + (t & 3) * 8;
    u16* AsW = As + t * 8;

    float4 a0 = ((const float4*)Arow)[0];
    float4 a1 = ((const float4*)Arow)[1];

    for (int k0 = 0; k0 < 256; k0 += 32) {
#pragma unroll
        for (int j = 0; j < 4; ++j) {
            int ch = j * 256 + t;
            ld16(Bt + (ch >> 2) * 256 + k0 + (ch & 3) * 8, Bs + j * 2048 + w * 512);
        }
        *(uint4*)AsW = pack8(a0, a1);
        __syncthreads();
        if (k0 + 32 < 256) {
            a0 = ((const float4*)(Arow + k0 + 32))[0];
            a1 = ((const float4*)(Arow + k0 + 32))[1];
        }
        uint4 af = *(const uint4*)(As + (w * 16 + l15) * 32 + q * 8);
#pragma unroll
        for (int c = 0; c < 16; ++c) {
            uint4 bf = *(const uint4*)(Bs + (c * 16 + l15) * 32 + q * 8);
            acc[c] = mfma_bf16(af, bf, acc[c]);
        }
        __syncthreads();
    }

#pragma unroll
    for (int c = 0; c < 16; ++c) {
        int col = c * 16 + l15;
        float bv = outb[bb * 256 + col];
#pragma unroll
        for (int r = 0; r < 4; ++r) {
            int row = r0 + w * 16 + q * 4 + r;
            C[(long)row * 256 + col] = acc[c][r] + bv;
        }
    }
}

// ---------------------------------------------------------------------------
// Split-K lam GEMM, 128x128 tiles: lamP[s][(b,e)][d] over chunk s of n.
// Grid (16, 2, S): A-sharing siblings differ by 16 in linear id -> same XCD.
// Both operands bf16 -> global_load_lds staging.
// ---------------------------------------------------------------------------
__global__ __launch_bounds__(256, 4) void gemm_splitk(const u16* __restrict__ VT,
                                                      const u16* __restrict__ PT,
                                                      float* __restrict__ lamP,
                                                      int chunk) {
    __shared__ __align__(16) u16 lds[8192];  // As 128x32, Bs 128x32
    u16* As = lds;
    u16* Bs = lds + 4096;

    const int t = threadIdx.x;
    const int r0 = blockIdx.x * 128;   // (b,e) rows
    const int c0 = blockIdx.y * 128;   // d cols
    const int s = blockIdx.z;
    const int bb = blockIdx.x >> 1;
    const long n0 = (long)s * chunk;
    const int w = t >> 6, lane = t & 63, l15 = lane & 15, q = lane >> 4;

    f32x4 acc[2][8];
#pragma unroll
    for (int rt = 0; rt < 2; ++rt)
#pragma unroll
        for (int c = 0; c < 8; ++c) acc[rt][c] = f32x4{0.f, 0.f, 0.f, 0.f};

    for (int k0 = 0; k0 < chunk; k0 += 32) {
#pragma unroll
        for (int j = 0; j < 2; ++j) {
            int ch = j * 256 + t;
            int br = ch >> 2;
            int bk = (ch & 3) * 8;
            ld16(VT + (long)(r0 + br) * 8192 + n0 + k0 + bk, As + j * 2048 + w * 512);
            ld16(PT + ((long)bb * 256 + c0 + br) * 8192 + n0 + k0 + bk,
                 Bs + j * 2048 + w * 512);
        }
        __syncthreads();
        uint4 af0 = *(const uint4*)(As + (w * 32 + l15) * 32 + q * 8);
        uint4 af1 = *(const uint4*)(As + (w * 32 + 16 + l15) * 32 + q * 8);
#pragma unroll
        for (int c = 0; c < 8; ++c) {
            uint4 bf = *(const uint4*)(Bs + (c * 16 + l15) * 32 + q * 8);
            acc[0][c] = mfma_bf16(af0, bf, acc[0][c]);
            acc[1][c] = mfma_bf16(af1, bf, acc[1][c]);
        }
        __syncthreads();
    }

    float* outp = lamP + (long)s * 524288;
#pragma unroll
    for (int rt = 0; rt < 2; ++rt)
#pragma unroll
        for (int c = 0; c < 8; ++c) {
            int col = c0 + c * 16 + l15;
#pragma unroll
            for (int r = 0; r < 4; ++r) {
                int row = r0 + w * 32 + rt * 16 + q * 4 + r;
                outp[(long)row * 256 + col] = acc[rt][c][r];
            }
        }
}

// ---------------------------------------------------------------------------
// lamT[i] = sum_s lamP[s][i]   (coalesced float4)
// ---------------------------------------------------------------------------
__global__ __launch_bounds__(256) void reduce_lam(const float* __restrict__ lamP,
                                                  float* __restrict__ lamT, int S) {
    int i = blockIdx.x * 256 + threadIdx.x;  // float4 index, 131072 total
    float4 v = ((const float4*)lamP)[i];
    for (int s = 1; s < S; ++s) {
        float4 p = ((const float4*)(lamP + (long)s * 524288))[i];
        v.x += p.x; v.y += p.y; v.z += p.z; v.w += p.w;
    }
    ((float4*)lamT)[i] = v;
}

// ---------------------------------------------------------------------------
// Fold GEMM: WfoldT[(b,e)][c] = sum_d bnT[(b,e)][d] * Wqb[c][d].
// 2048 rows x 256 cols, K=256.  Tile 64x64, grid (32,4) (A-sibs same XCD).
// ---------------------------------------------------------------------------
__global__ __launch_bounds__(256, 4) void gemm_fold(const u16* __restrict__ Abn,
                                                    const u16* __restrict__ Wqb,
                                                    u16* __restrict__ WfoldT) {
    __shared__ __align__(16) u16 lds[4096];  // As 64x32, Bs 64x32
    u16* As = lds;
    u16* Bs = lds + 2048;

    const int t = threadIdx.x;
    const int r0 = blockIdx.x * 64;
    const int c0 = blockIdx.y * 64;
    const int w = t >> 6, lane = t & 63, l15 = lane & 15, q = lane >> 4;

    f32x4 acc[4];
#pragma unroll
    for (int c = 0; c < 4; ++c) acc[c] = f32x4{0.f, 0.f, 0.f, 0.f};

    const int br = t >> 2;
    const int bk = (t & 3) * 8;

    for (int k0 = 0; k0 < 256; k0 += 32) {
        ld16(Abn + (long)(r0 + br) * 256 + k0 + bk, As + w * 512);
        ld16(Wqb + (long)(c0 + br) * 256 + k0 + bk, Bs + w * 512);
        __syncthreads();
        uint4 af = *(const uint4*)(As + (w * 16 + l15) * 32 + q * 8);
#pragma unroll
        for (int c = 0; c < 4; ++c) {
            uint4 bf = *(const uint4*)(Bs + (c * 16 + l15) * 32 + q * 8);
            acc[c] = mfma_bf16(af, bf, acc[c]);
        }
        __syncthreads();
    }

#pragma unroll
    for (int c = 0; c < 4; ++c) {
        int col = c0 + c * 16 + l15;
#pragma unroll
        for (int r = 0; r < 4; ++r) {
            int row = r0 + w * 16 + q * 4 + r;
            WfoldT[(long)row * 256 + col] = f2b(acc[c][r]);
        }
    }
}

// ---------------------------------------------------------------------------
// In-place softmax over each contiguous 8192-row of KT ([b*256+d][8192]).
// ---------------------------------------------------------------------------
__global__ __launch_bounds__(64) void softmax_rows(u16* __restrict__ KT) {
    const int row = blockIdx.x;
    const int lane = threadIdx.x;
    u16* p = KT + (long)row * 8192;

    uint4 buf[16];
#pragma unroll
    for (int i = 0; i < 16; ++i) buf[i] = *(const uint4*)(p + (i * 64 + lane) * 8);

    float m = -1e30f;
#pragma unroll
    for (int i = 0; i < 16; ++i) {
        const unsigned* u = (const unsigned*)&buf[i];
#pragma unroll
        for (int j = 0; j < 4; ++j) {
            m = fmaxf(m, fmaxf(b2f((u16)(u[j] & 0xffff)), b2f((u16)(u[j] >> 16))));
        }
    }
#pragma unroll
    for (int s = 32; s > 0; s >>= 1) m = fmaxf(m, __shfl_xor(m, s, 64));

    float sum = 0.f;
#pragma unroll
    for (int i = 0; i < 16; ++i) {
        const unsigned* u = (const unsigned*)&buf[i];
#pragma unroll
        for (int j = 0; j < 4; ++j) {
            sum += exp2f((b2f((u16)(u[j] & 0xffff)) - m) * LOG2E);
            sum += exp2f((b2f((u16)(u[j] >> 16)) - m) * LOG2E);
        }
    }
#pragma unroll
    for (int s = 32; s > 0; s >>= 1) sum += __shfl_xor(sum, s, 64);
    float rl = 1.0f / sum;

#pragma unroll
    for (int i = 0; i < 16; ++i) {
        unsigned* u = (unsigned*)&buf[i];
#pragma unroll
        for (int j = 0; j < 4; ++j) {
            float a = exp2f((b2f((u16)(u[j] & 0xffff)) - m) * LOG2E) * rl;
            float b = exp2f((b2f((u16)(u[j] >> 16)) - m) * LOG2E) * rl;
            u[j] = (unsigned)f2b(a) | ((unsigned)f2b(b) << 16);
        }
        *(uint4*)(p + (i * 64 + lane) * 8) = buf[i];
    }
}

// ---------------------------------------------------------------------------
// BatchNorm over lam^T[(b*256+e)][d]: stats per d over 2048 (b,e) values.
// ---------------------------------------------------------------------------
__global__ __launch_bounds__(256) void bn_kernel(const float* __restrict__ lamT,
                                                 const float* __restrict__ gamma,
                                                 const float* __restrict__ beta,
                                                 u16* __restrict__ bnT) {
    const int d = blockIdx.x;
    const int t = threadIdx.x;
    float vals[8];
    float s = 0.f, ss = 0.f;
#pragma unroll
    for (int i = 0; i < 8; ++i) {
        float v = lamT[(long)(i * 256 + t) * 256 + d];
        vals[i] = v;
        s += v;
        ss += v * v;
    }
#pragma unroll
    for (int sh = 32; sh > 0; sh >>= 1) {
        s += __shfl_xor(s, sh, 64);
        ss += __shfl_xor(ss, sh, 64);
    }
    __shared__ float red[8];
    int w = t >> 6;
    if ((t & 63) == 0) {
        red[w] = s;
        red[w + 4] = ss;
    }
    __syncthreads();
    s = red[0] + red[1] + red[2] + red[3];
    ss = red[4] + red[5] + red[6] + red[7];
    float mean = s * (1.f / 2048.f);
    float var = ss * (1.f / 2048.f) - mean * mean;
    float scale = gamma[d] * rsqrtf(var + 1e-5f);
    float shift = beta[d] - mean * scale;
#pragma unroll
    for (int i = 0; i < 8; ++i)
        bnT[(long)(i * 256 + t) * 256 + d] = f2b(vals[i] * scale + shift);
}

// ---------------------------------------------------------------------------
// outb[b][e] = sum_d bq[d] * bnT[b][e][d]   (folded query bias)
// ---------------------------------------------------------------------------
__global__ __launch_bounds__(256) void outb_kernel(const float* __restrict__ bq,
                                                   const u16* __restrict__ bnT,
                                                   float* __restrict__ outb) {
    int b = blockIdx.x, e = threadIdx.x;
    const u16* rowp = bnT + ((long)b * 256 + e) * 256;
    float s = 0.f;
    for (int dd = 0; dd < 256; ++dd) s += bq[dd] * b2f(rowp[dd]);
    outb[b * 256 + e] = s;
}

// ---------------------------------------------------------------------------
extern "C" void kernel_launch(void* const* d_in, const int* in_sizes, int n_in,
                              void* d_out, int out_size, void* d_ws, size_t ws_size,
                              hipStream_t stream) {
    const float* feat = (const float*)d_in[0];   // (8,8192,256) f32
    const float* W_qk = (const float*)d_in[1];   // (2,256,256) f32
    const float* b_qk = (const float*)d_in[2];   // (2,256) f32
    const float* W_v = (const float*)d_in[3];    // (256,256) f32
    const float* b_v = (const float*)d_in[4];    // (256,) f32
    const float* gamma = (const float*)d_in[5];  // (256,) f32
    const float* beta = (const float*)d_in[6];   // (256,) f32
    float* out = (float*)d_out;                  // (8,8192,256) f32

    char* ws = (char*)d_ws;
    u16* KT = (u16*)(ws);                        // [b][d][n] 33,554,432 B (P after softmax)
    u16* VT = (u16*)(ws + 33554432);             // [b][e][n] 33,554,432 B
    u16* WkT = (u16*)(ws + 67108864);            // 131072 B
    u16* WvT = (u16*)(ws + 67239936);            // 131072 B
    u16* Wqb = (u16*)(ws + 67371008);            // 131072 B
    const size_t base = 67502080;
    float* lamP = (float*)(ws + base);           // S * 2,097,152 B
    size_t avail = (ws_size > base) ? ws_size - base : 0;
    int S = (avail >= 16u * 2097152u) ? 16
          : (avail >= 8u * 2097152u) ? 8
          : (avail >= 4u * 2097152u) ? 4 : 2;
    // post-split-K buffers alias the dead P region (KT):
    float* lamT = (float*)ws;                    // 2,097,152 B
    u16* bnT = (u16*)(ws + 2097152);             // 1,048,576 B
    u16* WfoldT = (u16*)(ws + 3145728);          // 1,048,576 B
    float* outb = (float*)(ws + 4194304);        // 8,192 B

    // 1. weight prep
    prep_w<<<768, 256, 0, stream>>>(W_qk, W_v, WkT, WvT, Wqb);
    // 2. fused full-width K^T / V^T projection
    gemm_kv<<<1024, 256, 0, stream>>>(feat, WkT, WvT, b_qk + 256, b_v, KT, VT);
    // 3. in-place softmax over n -> P^T
    softmax_rows<<<2048, 64, 0, stream>>>(KT);
    // 4. split-K lam partials + reduce
    gemm_splitk<<<dim3(16, 2, S), 256, 0, stream>>>(VT, KT, lamP, 8192 / S);
    reduce_lam<<<512, 256, 0, stream>>>(lamP, lamT, S);
    // 5. BN -> bn^T bf16
    bn_kernel<<<256, 256, 0, stream>>>(lamT, gamma, beta, bnT);
    // 6. folded query bias
    outb_kernel<<<8, 256, 0, stream>>>(b_qk, bnT, outb);
    // 7. Wfold^T = bn^T @ Wq^T
    gemm_fold<<<dim3(32, 4), 256, 0, stream>>>(bnT, Wqb, WfoldT);
    // 8. out = X @ Wfold (+outb), full-width
    gemm_out<<<1024, 256, 0, stream>>>(feat, WfoldT, outb, out);
}